// Round 3
// baseline (249.890 us; speedup 1.0000x reference)
//
#include <hip/hip_runtime.h>
#include <math.h>

#define SEQ 4096
#define DM  1024
#define NH  16
#define DH  64
#define NS  4      // k-splits per q-tile

typedef _Float16 h16;
typedef __attribute__((ext_vector_type(4))) _Float16 h16x4;
typedef __attribute__((ext_vector_type(8))) _Float16 h16x8;
typedef __attribute__((ext_vector_type(4))) float f32x4;

// async global->LDS, 16B per lane, dest = wave-uniform base + lane*16
__device__ __forceinline__ void gload_lds16(const h16* g, h16* l) {
    __builtin_amdgcn_global_load_lds(
        (const __attribute__((address_space(1))) void*)g,
        (__attribute__((address_space(3))) void*)l, 16, 0, 0);
}

// ---------------------------------------------------------------------------
// Single fused fp32 -> fp16 conversion for x + all 4 weights.
// ---------------------------------------------------------------------------
__global__ __launch_bounds__(256) void cvt_all(const float* __restrict__ x,
                                               const float* __restrict__ wq,
                                               const float* __restrict__ wk,
                                               const float* __restrict__ wv,
                                               const float* __restrict__ wo,
                                               h16* __restrict__ dst) {
    const size_t SD4 = (size_t)SEQ * DM / 4;   // 1M float4s
    const size_t DD4 = (size_t)DM * DM / 4;    // 256K float4s
    const size_t i = (size_t)blockIdx.x * 256 + threadIdx.x;
    const float* src;
    size_t off;
    if (i < SD4) { src = x; off = i; }
    else {
        const size_t j = i - SD4;
        const int wsel = (int)(j >> 18);       // DD4 = 2^18
        off = j & (DD4 - 1);
        src = (wsel == 0) ? wq : (wsel == 1) ? wk : (wsel == 2) ? wv : wo;
    }
    const float4 v = ((const float4*)src)[off];
    h16x4 o = { (h16)v.x, (h16)v.y, (h16)v.z, (h16)v.w };
    ((h16x4*)dst)[i] = o;
}

// ---------------------------------------------------------------------------
// m97-style MFMA GEMM: 128x128 tile, BK=64 (two 32-slabs), global_load_lds
// width-16 staging into unpadded GT=32 layout. 4 waves, 4x4 frags.
// Outputs are written in attention-friendly layouts:
//   Q, K : head-blocked [NH][SEQ][64]   (each attn tile = contiguous 8KB)
//   V^T  : k-block-tiled [SEQ/64][DM][64] (each attn tile = contiguous 8KB,
//          and the h16x4 k-contig fragment stores are 128B-stride, not 8KB)
// ---------------------------------------------------------------------------
#define GT 32

// z = 0,1,2 -> Q (scaled), K, V^T outputs
__global__ __launch_bounds__(256) void gemm_qkv(const h16* __restrict__ xh,
                                                const h16* __restrict__ Wq,
                                                const h16* __restrict__ Wk,
                                                const h16* __restrict__ Wv,
                                                h16* __restrict__ Qh,
                                                h16* __restrict__ Kh,
                                                h16* __restrict__ Vth,
                                                float scl) {
    __shared__ h16 As[2][128 * GT];
    __shared__ h16 Bs[2][128 * GT];

    const int z    = blockIdx.z;
    const h16* B   = (z == 0) ? Wq : (z == 1) ? Wk : Wv;
    const int t    = threadIdx.x;
    const int lane = t & 63;
    const int w    = t >> 6;
    const int wm   = (w >> 1) * 64;
    const int wn   = (w & 1) * 64;
    const int l15  = lane & 15;
    const int lq   = lane >> 4;
    const int lq8  = lq * 8;
    const int m0   = blockIdx.y * 128;
    const int n0   = blockIdx.x * 128;
    const int K = DM, M = SEQ;

    const int srow = w * 16 + (lane >> 2);
    const int scol = (lane & 3) * 8;
    const h16* pa0 = xh + (size_t)(m0 + srow) * K + scol;
    const h16* pa1 = xh + (size_t)(m0 + 64 + srow) * K + scol;
    const h16* pb0 = B  + (size_t)(n0 + srow) * K + scol;
    const h16* pb1 = B  + (size_t)(n0 + 64 + srow) * K + scol;

    f32x4 acc[4][4] = {};

    for (int k0 = 0; k0 < K; k0 += 64) {
        __syncthreads();
        #pragma unroll
        for (int s = 0; s < 2; ++s) {
            const int ko = k0 + s * 32;
            gload_lds16(pa0 + ko, &As[s][w * 512]);
            gload_lds16(pa1 + ko, &As[s][2048 + w * 512]);
            gload_lds16(pb0 + ko, &Bs[s][w * 512]);
            gload_lds16(pb1 + ko, &Bs[s][2048 + w * 512]);
        }
        __syncthreads();

        #pragma unroll
        for (int s = 0; s < 2; ++s) {
            h16x8 af[4], bf[4];
            #pragma unroll
            for (int i = 0; i < 4; ++i)
                af[i] = *(const h16x8*)&As[s][(wm + i * 16 + l15) * GT + lq8];
            #pragma unroll
            for (int j = 0; j < 4; ++j)
                bf[j] = *(const h16x8*)&Bs[s][(wn + j * 16 + l15) * GT + lq8];
            #pragma unroll
            for (int i = 0; i < 4; ++i)
                #pragma unroll
                for (int j = 0; j < 4; ++j)
                    acc[i][j] = __builtin_amdgcn_mfma_f32_16x16x32_f16(af[i], bf[j], acc[i][j], 0, 0, 0);
        }
    }

    const int cr = wm + lq * 4;
    const int cc = wn + l15;
    if (z == 2) {   // V^T k-block-tiled: [(k>>6)][d][k&63], h16x4 k-contig
        #pragma unroll
        for (int i = 0; i < 4; ++i)
            #pragma unroll
            for (int j = 0; j < 4; ++j) {
                const int gm0 = m0 + cr + i * 16;   // k index (r-contig, 4-aligned)
                const int gn  = n0 + cc + j * 16;   // d index
                h16x4 v = { (h16)acc[i][j][0], (h16)acc[i][j][1],
                            (h16)acc[i][j][2], (h16)acc[i][j][3] };
                *(h16x4*)(Vth + ((size_t)(gm0 >> 6) * DM + gn) * 64 + (gm0 & 63)) = v;
            }
    } else {        // Q/K head-blocked: [(d>>6)][seq][d&63]
        h16* Og = (z == 0) ? Qh : Kh;
        const float e = (z == 0) ? scl : 1.0f;
        #pragma unroll
        for (int i = 0; i < 4; ++i)
            #pragma unroll
            for (int j = 0; j < 4; ++j)
                #pragma unroll
                for (int r = 0; r < 4; ++r) {
                    const int gm = m0 + cr + i * 16 + r;   // seq
                    const int gn = n0 + cc + j * 16;       // d
                    Og[((size_t)(gn >> 6) * SEQ + gm) * 64 + (gn & 63)] = (h16)(acc[i][j][r] * e);
                }
    }
}

// out[M][N] (f32) = AO (h16) @ Wo^T (h16). 64x128 tile -> grid 512 = 2/CU.
__global__ __launch_bounds__(256) void gemm_out(const h16* __restrict__ A,
                                                const h16* __restrict__ B,
                                                float* __restrict__ C) {
    __shared__ h16 As[2][64 * GT];
    __shared__ h16 Bs[2][128 * GT];

    const int t    = threadIdx.x;
    const int lane = t & 63;
    const int w    = t >> 6;
    const int wm   = (w >> 1) * 32;
    const int wn   = (w & 1) * 64;
    const int l15  = lane & 15;
    const int lq   = lane >> 4;
    const int lq8  = lq * 8;
    const int m0   = blockIdx.y * 64;
    const int n0   = blockIdx.x * 128;
    const int K = DM, N = DM;

    const int srow = w * 16 + (lane >> 2);
    const int scol = (lane & 3) * 8;
    const h16* pa0 = A + (size_t)(m0 + srow) * K + scol;
    const h16* pb0 = B + (size_t)(n0 + srow) * K + scol;
    const h16* pb1 = B + (size_t)(n0 + 64 + srow) * K + scol;

    f32x4 acc[2][4] = {};

    for (int k0 = 0; k0 < K; k0 += 64) {
        __syncthreads();
        #pragma unroll
        for (int s = 0; s < 2; ++s) {
            const int ko = k0 + s * 32;
            gload_lds16(pa0 + ko, &As[s][w * 512]);
            gload_lds16(pb0 + ko, &Bs[s][w * 512]);
            gload_lds16(pb1 + ko, &Bs[s][2048 + w * 512]);
        }
        __syncthreads();

        #pragma unroll
        for (int s = 0; s < 2; ++s) {
            h16x8 af[2], bf[4];
            #pragma unroll
            for (int i = 0; i < 2; ++i)
                af[i] = *(const h16x8*)&As[s][(wm + i * 16 + l15) * GT + lq8];
            #pragma unroll
            for (int j = 0; j < 4; ++j)
                bf[j] = *(const h16x8*)&Bs[s][(wn + j * 16 + l15) * GT + lq8];
            #pragma unroll
            for (int i = 0; i < 2; ++i)
                #pragma unroll
                for (int j = 0; j < 4; ++j)
                    acc[i][j] = __builtin_amdgcn_mfma_f32_16x16x32_f16(af[i], bf[j], acc[i][j], 0, 0, 0);
        }
    }

    const int cr = wm + lq * 4;
    const int cc = wn + l15;
    #pragma unroll
    for (int i = 0; i < 2; ++i)
        #pragma unroll
        for (int j = 0; j < 4; ++j)
            #pragma unroll
            for (int r = 0; r < 4; ++r)
                C[(size_t)(m0 + cr + i * 16 + r) * N + n0 + cc + j * 16] = acc[i][j][r];
}

// ---------------------------------------------------------------------------
// SPLIT-K MFMA flash attention (causal), S^T formulation, exp2 domain.
// Register-P PV; Vs stride VST=72 (PV b64 reads at bank minimum).
// Ks XOR swizzle: column ^= ((row>>2)&3)<<3 — kills the quarter-wave 2x
// bank conflict of the stride-80 ds_read_b128 (the 8.5M residual).
// Q/K inputs are head-blocked [NH][SEQ][64]; V^T is k-block-tiled
// [SEQ/64][DM][64] -> every staged tile is one contiguous 8KB chunk.
// ---------------------------------------------------------------------------
#define AST 80
#define VST 72

__global__ __launch_bounds__(256, 6) void flash_attn_split(
        const h16* __restrict__ Qg, const h16* __restrict__ Kg,
        const h16* __restrict__ Vt, h16* __restrict__ OP,
        float* __restrict__ Mb, float* __restrict__ Lb) {
    __shared__ h16 Ks[64 * AST];   // [k_local][d], col XOR-swizzled
    __shared__ h16 Vs[64 * VST];   // [d][k_local]

    const int qt   = 63 - (int)blockIdx.y;   // big chunks dispatch first
    const int hh   = blockIdx.x;
    const int sp   = blockIdx.z;
    const int t    = threadIdx.x;
    const int lane = t & 63;
    const int w    = t >> 6;
    const int l15  = lane & 15;
    const int lq   = lane >> 4;
    const int lq8  = lq * 8;
    const int hc   = hh * DH;
    const int q0   = qt * 64;
    const int q_loc = w * 16 + l15;

    const int ntile = qt + 1;
    const int chunk = (ntile + NS - 1) / NS;
    const int kts   = sp * chunk;
    const int kte   = (kts + chunk < ntile) ? (kts + chunk) : ntile;

    const int r1 = t >> 3;             // 0..31
    const int r2 = r1 + 32;
    const int c1 = (t & 7) * 8;
    // Ks column swizzle for writes: rows r1 and r2=r1+32 share (r>>2)&3
    const int sw  = ((r1 >> 2) & 3) << 3;
    const int c1s = c1 ^ sw;
    // Ks column swizzle for frag reads: row = jj*16 + l15 (and q_loc = w*16
    // + l15) -> (row>>2)&3 == (l15>>2)&3 for all jj/w.
    const int rsw = ((l15 >> 2) & 3) << 3;

    // head-blocked bases
    const h16* Qb = Qg + (size_t)hh * SEQ * 64;
    const h16* Kb = Kg + (size_t)hh * SEQ * 64;

    // stage Q into Ks (consumed into regs before loop overwrites)
    *(h16x8*)&Ks[r1 * AST + c1s] = *(const h16x8*)(Qb + (size_t)(q0 + r1) * 64 + c1);
    *(h16x8*)&Ks[r2 * AST + c1s] = *(const h16x8*)(Qb + (size_t)(q0 + r2) * 64 + c1);

    // preload first K/V tile of this split (kts <= 48 always: in-bounds)
    const int kb0 = kts * 64;
    h16x8 kv1 = *(const h16x8*)(Kb + (size_t)(kb0 + r1) * 64 + c1);
    h16x8 kv2 = *(const h16x8*)(Kb + (size_t)(kb0 + r2) * 64 + c1);
    h16x8 vv1 = *(const h16x8*)(Vt + ((size_t)kts * DM + hc + r1) * 64 + c1);
    h16x8 vv2 = *(const h16x8*)(Vt + ((size_t)kts * DM + hc + r2) * 64 + c1);

    __syncthreads();
    h16x8 qf[2];
    qf[0] = *(const h16x8*)&Ks[q_loc * AST + (lq8 ^ rsw)];
    qf[1] = *(const h16x8*)&Ks[q_loc * AST + ((32 + lq8) ^ rsw)];

    float m_st = -1e30f, l_st = 0.0f;   // l_st is a PER-LANE partial sum
    f32x4 o[4] = {};

    for (int kt = kts; kt < kte; ++kt) {
        __syncthreads();   // prior frag/qf reads drained
        *(h16x8*)&Ks[r1 * AST + c1s] = kv1;
        *(h16x8*)&Ks[r2 * AST + c1s] = kv2;
        *(h16x8*)&Vs[r1 * VST + c1] = vv1;
        *(h16x8*)&Vs[r2 * VST + c1] = vv2;
        __syncthreads();
        if (kt + 1 < kte) {   // prefetch next K/V tile (overlaps compute)
            const int k0n = (kt + 1) * 64;
            kv1 = *(const h16x8*)(Kb + (size_t)(k0n + r1) * 64 + c1);
            kv2 = *(const h16x8*)(Kb + (size_t)(k0n + r2) * 64 + c1);
            vv1 = *(const h16x8*)(Vt + ((size_t)(kt + 1) * DM + hc + r1) * 64 + c1);
            vv2 = *(const h16x8*)(Vt + ((size_t)(kt + 1) * DM + hc + r2) * 64 + c1);
        }

        // ---- S^T = K Q^T (one q per lane in C-layout cols) ----
        f32x4 s[4] = {};
        #pragma unroll
        for (int kc = 0; kc < 2; ++kc)
            #pragma unroll
            for (int jj = 0; jj < 4; ++jj) {
                const h16x8 kf = *(const h16x8*)&Ks[(jj * 16 + l15) * AST + ((kc * 32 + lq8) ^ rsw)];
                s[jj] = __builtin_amdgcn_mfma_f32_16x16x32_f16(kf, qf[kc], s[jj], 0, 0, 0);
            }

        // ---- online softmax (in-register) ----
        if (kt == qt) {   // diagonal tile (only last split reaches it)
            #pragma unroll
            for (int jj = 0; jj < 4; ++jj)
                #pragma unroll
                for (int r = 0; r < 4; ++r)
                    if ((jj * 16 + lq * 4 + r) > q_loc) s[jj][r] = -1e30f;
        }
        float mx = -1e30f;
        #pragma unroll
        for (int jj = 0; jj < 4; ++jj)
            #pragma unroll
            for (int r = 0; r < 4; ++r)
                mx = fmaxf(mx, s[jj][r]);
        mx = fmaxf(mx, __shfl_xor(mx, 16, 64));
        mx = fmaxf(mx, __shfl_xor(mx, 32, 64));
        // defer-max: only rescale when tile max exceeds running max by >5
        // (exp2 domain: P bounded by 2^5 = 32, safe in fp16 partials).
        // mx is identical across the 4 lanes of a q-row -> coherent branch.
        if (mx > m_st + 5.0f) {
            const float alpha = exp2f(m_st - mx);
            m_st = mx;
            l_st *= alpha;
            #pragma unroll
            for (int jj = 0; jj < 4; ++jj)
                #pragma unroll
                for (int r = 0; r < 4; ++r)
                    o[jj][r] *= alpha;
        }

        // P = exp2(S - m). C-layout of s[jj] == B-operand layout of
        // mfma_f32_16x16x16f16 (k = lq*4 + e within block jj, col = l15):
        // feed PV directly, no LDS round-trip.
        h16x4 pk[4];
        #pragma unroll
        for (int jj = 0; jj < 4; ++jj) {
            const float p0 = exp2f(s[jj][0] - m_st);
            const float p1 = exp2f(s[jj][1] - m_st);
            const float p2 = exp2f(s[jj][2] - m_st);
            const float p3 = exp2f(s[jj][3] - m_st);
            l_st += (p0 + p1) + (p2 + p3);
            pk[jj] = h16x4{ (h16)p0, (h16)p1, (h16)p2, (h16)p3 };
        }

        // ---- O^T += V^T P^T (16x16x16 MFMA, P from registers) ----
        #pragma unroll
        for (int dd = 0; dd < 4; ++dd)
            #pragma unroll
            for (int jj = 0; jj < 4; ++jj) {
                const h16x4 vf = *(const h16x4*)&Vs[(dd * 16 + l15) * VST + jj * 16 + lq * 4];
                o[dd] = __builtin_amdgcn_mfma_f32_16x16x16f16(vf, pk[jj], o[dd], 0, 0, 0);
            }
    }

    // fold the per-lane partial sums (q-row spread over 4 lanes via lq)
    l_st += __shfl_xor(l_st, 16, 64);
    l_st += __shfl_xor(l_st, 32, 64);

    // ---- epilogue: write UNNORMALIZED partial O + (m, l) ----
    h16* const op = OP + (size_t)sp * SEQ * DM;
    const size_t qg = (size_t)(q0 + q_loc) * DM + hc;
    #pragma unroll
    for (int jj = 0; jj < 4; ++jj) {
        h16x4 ov = { (h16)o[jj][0], (h16)o[jj][1],
                     (h16)o[jj][2], (h16)o[jj][3] };
        *(h16x4*)(op + qg + jj * 16 + lq * 4) = ov;
    }
    if (lq == 0) {   // one lane per q-row (all lq agree after xor16/32)
        const size_t mi = ((size_t)sp * NH + hh) * SEQ + q0 + q_loc;
        Mb[mi] = m_st;
        Lb[mi] = l_st;
    }
}

// ---------------------------------------------------------------------------
// Combine NS partials: O = sum_s w_s*O_s / sum_s w_s*l_s, w_s = exp2(m_s-m*).
// One thread per 4 d-columns of one q-row.
// ---------------------------------------------------------------------------
__global__ __launch_bounds__(256) void combine(const h16* __restrict__ OP,
                                               const float* __restrict__ Mb,
                                               const float* __restrict__ Lb,
                                               h16* __restrict__ AOh) {
    const int i  = blockIdx.x * 256 + threadIdx.x;   // 1M threads
    const int q  = i >> 8;
    const int c4 = (i & 255) * 4;
    const int hh = c4 >> 6;

    float ms[NS], ls[NS];
    float mstar = -1e30f;
    #pragma unroll
    for (int s = 0; s < NS; ++s) {
        const size_t mi = ((size_t)s * NH + hh) * SEQ + q;
        ms[s] = Mb[mi];
        ls[s] = Lb[mi];
        mstar = fmaxf(mstar, ms[s]);
    }
    float L = 0.0f;
    float acc[4] = {};
    #pragma unroll
    for (int s = 0; s < NS; ++s) {
        const float ws = exp2f(ms[s] - mstar);
        L += ls[s] * ws;
        const h16x4 ov = *(const h16x4*)(OP + (size_t)s * SEQ * DM + (size_t)q * DM + c4);
        acc[0] += ws * (float)ov[0];
        acc[1] += ws * (float)ov[1];
        acc[2] += ws * (float)ov[2];
        acc[3] += ws * (float)ov[3];
    }
    const float inv = 1.0f / L;
    h16x4 r = { (h16)(acc[0] * inv), (h16)(acc[1] * inv),
                (h16)(acc[2] * inv), (h16)(acc[3] * inv) };
    *(h16x4*)(AOh + (size_t)q * DM + c4) = r;
}

// ---------------------------------------------------------------------------
extern "C" void kernel_launch(void* const* d_in, const int* in_sizes, int n_in,
                              void* d_out, int out_size, void* d_ws, size_t ws_size,
                              hipStream_t stream) {
    const float* x  = (const float*)d_in[0];
    const float* Wq = (const float*)d_in[1];
    const float* Wk = (const float*)d_in[2];
    const float* Wv = (const float*)d_in[3];
    const float* Wo = (const float*)d_in[4];
    float* out = (float*)d_out;

    const size_t SD = (size_t)SEQ * DM;   // 4M
    const size_t DD = (size_t)DM * DM;    // 1M

    h16* xh  = (h16*)d_ws;                // cvt_all relies on this contiguity
    h16* wqh = xh + SD;
    h16* wkh = wqh + DD;
    h16* wvh = wkh + DD;
    h16* woh = wvh + DD;
    h16* Qh  = woh + DD;                  // head-blocked [NH][SEQ][64]
    h16* Kh  = Qh + SD;                   // head-blocked [NH][SEQ][64]
    h16* Vth = Kh + SD;                   // k-block-tiled [SEQ/64][DM][64]
    h16* AOh = Vth + SD;
    h16* OP  = AOh + SD;                  // NS partial O buffers
    float* Mb = (float*)(OP + (size_t)NS * SD);
    float* Lb = Mb + (size_t)NS * NH * SEQ;

    const dim3 blk(256);

    cvt_all<<<(int)((SD + 4 * DD) / 4 / 256), blk, 0, stream>>>(x, Wq, Wk, Wv, Wo, xh);

    // Q pre-scaled by 1/sqrt(DH) * log2(e) for the exp2-domain softmax
    const float SCL = 0.125f * 1.44269504088896340736f;

    gemm_qkv<<<dim3(DM / 128, SEQ / 128, 3), blk, 0, stream>>>(
        xh, wqh, wkh, wvh, Qh, Kh, Vth, SCL);

    flash_attn_split<<<dim3(NH, 64, NS), blk, 0, stream>>>(Qh, Kh, Vth, OP, Mb, Lb);

    combine<<<(int)(SD / 4 / 256), blk, 0, stream>>>(OP, Mb, Lb, AOh);

    gemm_out<<<dim3(DM / 128, SEQ / 64), blk, 0, stream>>>(AOh, woh, out);
}

// Round 4
// 222.116 us; speedup vs baseline: 1.1250x; 1.1250x over previous
//
#include <hip/hip_runtime.h>
#include <math.h>

#define SEQ 4096
#define DM  1024
#define NH  16
#define DH  64
#define NS  4      // k-splits per q-tile

typedef _Float16 h16;
typedef __attribute__((ext_vector_type(4))) _Float16 h16x4;
typedef __attribute__((ext_vector_type(8))) _Float16 h16x8;
typedef __attribute__((ext_vector_type(4))) float f32x4;

// async global->LDS, 16B per lane, dest = wave-uniform base + lane*16
__device__ __forceinline__ void gload_lds16(const h16* g, h16* l) {
    __builtin_amdgcn_global_load_lds(
        (const __attribute__((address_space(1))) void*)g,
        (__attribute__((address_space(3))) void*)l, 16, 0, 0);
}

// ---------------------------------------------------------------------------
// Single fused fp32 -> fp16 conversion for x + all 4 weights.
// ---------------------------------------------------------------------------
__global__ __launch_bounds__(256) void cvt_all(const float* __restrict__ x,
                                               const float* __restrict__ wq,
                                               const float* __restrict__ wk,
                                               const float* __restrict__ wv,
                                               const float* __restrict__ wo,
                                               h16* __restrict__ dst) {
    const size_t SD4 = (size_t)SEQ * DM / 4;   // 1M float4s
    const size_t DD4 = (size_t)DM * DM / 4;    // 256K float4s
    const size_t i = (size_t)blockIdx.x * 256 + threadIdx.x;
    const float* src;
    size_t off;
    if (i < SD4) { src = x; off = i; }
    else {
        const size_t j = i - SD4;
        const int wsel = (int)(j >> 18);       // DD4 = 2^18
        off = j & (DD4 - 1);
        src = (wsel == 0) ? wq : (wsel == 1) ? wk : (wsel == 2) ? wv : wo;
    }
    const float4 v = ((const float4*)src)[off];
    h16x4 o = { (h16)v.x, (h16)v.y, (h16)v.z, (h16)v.w };
    ((h16x4*)dst)[i] = o;
}

// ---------------------------------------------------------------------------
// m97-style MFMA GEMM: 128x128 tile, BK=64 (two 32-slabs), global_load_lds
// width-16 staging into unpadded GT=32 layout. 4 waves, 4x4 frags.
// Layouts: Q/K plain [SEQ][DM] (scaled Q), V^T [DM][SEQ].  (round-0 state;
// the round-3 tiled layouts caused a 3x HBM-write blowup — reverted.)
// ---------------------------------------------------------------------------
#define GT 32

// z = 0,1,2 -> Q (scaled), K, V^T outputs
__global__ __launch_bounds__(256) void gemm_qkv(const h16* __restrict__ xh,
                                                const h16* __restrict__ Wq,
                                                const h16* __restrict__ Wk,
                                                const h16* __restrict__ Wv,
                                                h16* __restrict__ Qh,
                                                h16* __restrict__ Kh,
                                                h16* __restrict__ Vth,
                                                float scl) {
    __shared__ h16 As[2][128 * GT];
    __shared__ h16 Bs[2][128 * GT];

    const int z    = blockIdx.z;
    const h16* B   = (z == 0) ? Wq : (z == 1) ? Wk : Wv;
    const int t    = threadIdx.x;
    const int lane = t & 63;
    const int w    = t >> 6;
    const int wm   = (w >> 1) * 64;
    const int wn   = (w & 1) * 64;
    const int l15  = lane & 15;
    const int lq   = lane >> 4;
    const int lq8  = lq * 8;
    const int m0   = blockIdx.y * 128;
    const int n0   = blockIdx.x * 128;
    const int K = DM, M = SEQ, N = DM;

    const int srow = w * 16 + (lane >> 2);
    const int scol = (lane & 3) * 8;
    const h16* pa0 = xh + (size_t)(m0 + srow) * K + scol;
    const h16* pa1 = xh + (size_t)(m0 + 64 + srow) * K + scol;
    const h16* pb0 = B  + (size_t)(n0 + srow) * K + scol;
    const h16* pb1 = B  + (size_t)(n0 + 64 + srow) * K + scol;

    f32x4 acc[4][4] = {};

    for (int k0 = 0; k0 < K; k0 += 64) {
        __syncthreads();
        #pragma unroll
        for (int s = 0; s < 2; ++s) {
            const int ko = k0 + s * 32;
            gload_lds16(pa0 + ko, &As[s][w * 512]);
            gload_lds16(pa1 + ko, &As[s][2048 + w * 512]);
            gload_lds16(pb0 + ko, &Bs[s][w * 512]);
            gload_lds16(pb1 + ko, &Bs[s][2048 + w * 512]);
        }
        __syncthreads();

        #pragma unroll
        for (int s = 0; s < 2; ++s) {
            h16x8 af[4], bf[4];
            #pragma unroll
            for (int i = 0; i < 4; ++i)
                af[i] = *(const h16x8*)&As[s][(wm + i * 16 + l15) * GT + lq8];
            #pragma unroll
            for (int j = 0; j < 4; ++j)
                bf[j] = *(const h16x8*)&Bs[s][(wn + j * 16 + l15) * GT + lq8];
            #pragma unroll
            for (int i = 0; i < 4; ++i)
                #pragma unroll
                for (int j = 0; j < 4; ++j)
                    acc[i][j] = __builtin_amdgcn_mfma_f32_16x16x32_f16(af[i], bf[j], acc[i][j], 0, 0, 0);
        }
    }

    const int cr = wm + lq * 4;
    const int cc = wn + l15;
    if (z == 2) {   // V^T: h16 [N][M], vectorized along M
        #pragma unroll
        for (int i = 0; i < 4; ++i)
            #pragma unroll
            for (int j = 0; j < 4; ++j) {
                const int gm0 = m0 + cr + i * 16;
                const int gn  = n0 + cc + j * 16;
                h16x4 v = { (h16)acc[i][j][0], (h16)acc[i][j][1],
                            (h16)acc[i][j][2], (h16)acc[i][j][3] };
                *(h16x4*)(Vth + (size_t)gn * M + gm0) = v;
            }
    } else {
        h16* Og = (z == 0) ? Qh : Kh;
        const float e = (z == 0) ? scl : 1.0f;
        #pragma unroll
        for (int i = 0; i < 4; ++i)
            #pragma unroll
            for (int j = 0; j < 4; ++j)
                #pragma unroll
                for (int r = 0; r < 4; ++r) {
                    const int gm = m0 + cr + i * 16 + r;
                    const int gn = n0 + cc + j * 16;
                    Og[(size_t)gm * N + gn] = (h16)(acc[i][j][r] * e);
                }
    }
}

// out[M][N] (f32) = AO (h16) @ Wo^T (h16). 64x128 tile -> grid 512 = 2/CU.
__global__ __launch_bounds__(256) void gemm_out(const h16* __restrict__ A,
                                                const h16* __restrict__ B,
                                                float* __restrict__ C) {
    __shared__ h16 As[2][64 * GT];
    __shared__ h16 Bs[2][128 * GT];

    const int t    = threadIdx.x;
    const int lane = t & 63;
    const int w    = t >> 6;
    const int wm   = (w >> 1) * 32;
    const int wn   = (w & 1) * 64;
    const int l15  = lane & 15;
    const int lq   = lane >> 4;
    const int lq8  = lq * 8;
    const int m0   = blockIdx.y * 64;
    const int n0   = blockIdx.x * 128;
    const int K = DM, N = DM;

    const int srow = w * 16 + (lane >> 2);
    const int scol = (lane & 3) * 8;
    const h16* pa0 = A + (size_t)(m0 + srow) * K + scol;
    const h16* pb0 = B + (size_t)(n0 + srow) * K + scol;
    const h16* pb1 = B + (size_t)(n0 + 64 + srow) * K + scol;

    f32x4 acc[2][4] = {};

    for (int k0 = 0; k0 < K; k0 += 64) {
        __syncthreads();
        #pragma unroll
        for (int s = 0; s < 2; ++s) {
            const int ko = k0 + s * 32;
            gload_lds16(pa0 + ko, &As[s][w * 512]);
            gload_lds16(pb0 + ko, &Bs[s][w * 512]);
            gload_lds16(pb1 + ko, &Bs[s][2048 + w * 512]);
        }
        __syncthreads();

        #pragma unroll
        for (int s = 0; s < 2; ++s) {
            h16x8 af[2], bf[4];
            #pragma unroll
            for (int i = 0; i < 2; ++i)
                af[i] = *(const h16x8*)&As[s][(wm + i * 16 + l15) * GT + lq8];
            #pragma unroll
            for (int j = 0; j < 4; ++j)
                bf[j] = *(const h16x8*)&Bs[s][(wn + j * 16 + l15) * GT + lq8];
            #pragma unroll
            for (int i = 0; i < 2; ++i)
                #pragma unroll
                for (int j = 0; j < 4; ++j)
                    acc[i][j] = __builtin_amdgcn_mfma_f32_16x16x32_f16(af[i], bf[j], acc[i][j], 0, 0, 0);
        }
    }

    const int cr = wm + lq * 4;
    const int cc = wn + l15;
    #pragma unroll
    for (int i = 0; i < 2; ++i)
        #pragma unroll
        for (int j = 0; j < 4; ++j)
            #pragma unroll
            for (int r = 0; r < 4; ++r)
                C[(size_t)(m0 + cr + i * 16 + r) * N + n0 + cc + j * 16] = acc[i][j][r];
}

// ---------------------------------------------------------------------------
// SPLIT-K MFMA flash attention (causal), S^T formulation, exp2 domain.
// Register-P PV (S^T C-layout == 16x16x16 B-operand layout, no P LDS trip).
// THIS ROUND: double-buffered Ks/Vs, ONE barrier per k-tile. Tile kt+1's
// LDS writes (from regs) overlap stragglers' reads of the other buffer:
// reads of buf b at iter kt drain at barrier kt+1; buf b is rewritten only
// at iter kt+2 (after that barrier) -> safe with a single barrier.
// Q fragments read directly to registers (one-time, no LDS staging).
// ---------------------------------------------------------------------------
#define AST 80
#define VST 72

__global__ __launch_bounds__(256, 4) void flash_attn_split(
        const h16* __restrict__ Qg, const h16* __restrict__ Kg,
        const h16* __restrict__ Vt, h16* __restrict__ OP,
        float* __restrict__ Mb, float* __restrict__ Lb) {
    __shared__ h16 Ks[2][64 * AST];   // [buf][k_local][d]
    __shared__ h16 Vs[2][64 * VST];   // [buf][d][k_local]

    const int qt   = 63 - (int)blockIdx.y;   // big chunks dispatch first
    const int hh   = blockIdx.x;
    const int sp   = blockIdx.z;
    const int t    = threadIdx.x;
    const int lane = t & 63;
    const int w    = t >> 6;
    const int l15  = lane & 15;
    const int lq   = lane >> 4;
    const int lq8  = lq * 8;
    const int hc   = hh * DH;
    const int q0   = qt * 64;
    const int q_loc = w * 16 + l15;

    const int ntile = qt + 1;
    const int chunk = (ntile + NS - 1) / NS;
    const int kts   = sp * chunk;
    const int kte   = (kts + chunk < ntile) ? (kts + chunk) : ntile;

    const int r1 = t >> 3;             // 0..31
    const int r2 = r1 + 32;
    const int c1 = (t & 7) * 8;

    // Q fragments: direct global reads (one-time per block)
    const size_t qrow = (size_t)(q0 + q_loc) * DM + hc;
    h16x8 qf[2];
    qf[0] = *(const h16x8*)(Qg + qrow + lq8);
    qf[1] = *(const h16x8*)(Qg + qrow + 32 + lq8);

    // preload first K/V tile of this split (kts <= 48 always: in-bounds)
    const int kb0 = kts * 64;
    h16x8 kv1 = *(const h16x8*)(Kg + (size_t)(kb0 + r1) * DM + hc + c1);
    h16x8 kv2 = *(const h16x8*)(Kg + (size_t)(kb0 + r2) * DM + hc + c1);
    h16x8 vv1 = *(const h16x8*)(Vt + (size_t)(hc + r1) * SEQ + kb0 + c1);
    h16x8 vv2 = *(const h16x8*)(Vt + (size_t)(hc + r2) * SEQ + kb0 + c1);

    float m_st = -1e30f, l_st = 0.0f;   // l_st is a PER-LANE partial sum
    f32x4 o[4] = {};
    int bb = 0;

    for (int kt = kts; kt < kte; ++kt) {
        // stage tile kt into buf bb (regs loaded last iteration)
        *(h16x8*)&Ks[bb][r1 * AST + c1] = kv1;
        *(h16x8*)&Ks[bb][r2 * AST + c1] = kv2;
        *(h16x8*)&Vs[bb][r1 * VST + c1] = vv1;
        *(h16x8*)&Vs[bb][r2 * VST + c1] = vv2;
        __syncthreads();
        if (kt + 1 < kte) {   // prefetch next K/V tile (covered by compute)
            const int k0n = (kt + 1) * 64;
            kv1 = *(const h16x8*)(Kg + (size_t)(k0n + r1) * DM + hc + c1);
            kv2 = *(const h16x8*)(Kg + (size_t)(k0n + r2) * DM + hc + c1);
            vv1 = *(const h16x8*)(Vt + (size_t)(hc + r1) * SEQ + k0n + c1);
            vv2 = *(const h16x8*)(Vt + (size_t)(hc + r2) * SEQ + k0n + c1);
        }

        // ---- S^T = K Q^T (one q per lane in C-layout cols) ----
        f32x4 s[4] = {};
        #pragma unroll
        for (int kc = 0; kc < 2; ++kc)
            #pragma unroll
            for (int jj = 0; jj < 4; ++jj) {
                const h16x8 kf = *(const h16x8*)&Ks[bb][(jj * 16 + l15) * AST + kc * 32 + lq8];
                s[jj] = __builtin_amdgcn_mfma_f32_16x16x32_f16(kf, qf[kc], s[jj], 0, 0, 0);
            }

        // ---- online softmax (in-register) ----
        if (kt == qt) {   // diagonal tile (only last split reaches it)
            #pragma unroll
            for (int jj = 0; jj < 4; ++jj)
                #pragma unroll
                for (int r = 0; r < 4; ++r)
                    if ((jj * 16 + lq * 4 + r) > q_loc) s[jj][r] = -1e30f;
        }
        float mx = -1e30f;
        #pragma unroll
        for (int jj = 0; jj < 4; ++jj)
            #pragma unroll
            for (int r = 0; r < 4; ++r)
                mx = fmaxf(mx, s[jj][r]);
        mx = fmaxf(mx, __shfl_xor(mx, 16, 64));
        mx = fmaxf(mx, __shfl_xor(mx, 32, 64));
        // defer-max: only rescale when tile max exceeds running max by >5
        // (exp2 domain: P bounded by 2^5 = 32, safe in fp16 partials).
        // mx is identical across the 4 lanes of a q-row -> coherent branch.
        if (mx > m_st + 5.0f) {
            const float alpha = exp2f(m_st - mx);
            m_st = mx;
            l_st *= alpha;
            #pragma unroll
            for (int jj = 0; jj < 4; ++jj)
                #pragma unroll
                for (int r = 0; r < 4; ++r)
                    o[jj][r] *= alpha;
        }

        // P = exp2(S - m). C-layout of s[jj] == B-operand layout of
        // mfma_f32_16x16x16f16 (k = lq*4 + e within block jj, col = l15):
        // feed PV directly, no LDS round-trip.
        h16x4 pk[4];
        #pragma unroll
        for (int jj = 0; jj < 4; ++jj) {
            const float p0 = exp2f(s[jj][0] - m_st);
            const float p1 = exp2f(s[jj][1] - m_st);
            const float p2 = exp2f(s[jj][2] - m_st);
            const float p3 = exp2f(s[jj][3] - m_st);
            l_st += (p0 + p1) + (p2 + p3);
            pk[jj] = h16x4{ (h16)p0, (h16)p1, (h16)p2, (h16)p3 };
        }

        // ---- O^T += V^T P^T (16x16x16 MFMA, P from registers) ----
        #pragma unroll
        for (int dd = 0; dd < 4; ++dd)
            #pragma unroll
            for (int jj = 0; jj < 4; ++jj) {
                const h16x4 vf = *(const h16x4*)&Vs[bb][(dd * 16 + l15) * VST + jj * 16 + lq * 4];
                o[dd] = __builtin_amdgcn_mfma_f32_16x16x16f16(vf, pk[jj], o[dd], 0, 0, 0);
            }

        bb ^= 1;
    }

    // fold the per-lane partial sums (q-row spread over 4 lanes via lq)
    l_st += __shfl_xor(l_st, 16, 64);
    l_st += __shfl_xor(l_st, 32, 64);

    // ---- epilogue: write UNNORMALIZED partial O + (m, l) ----
    h16* const op = OP + (size_t)sp * SEQ * DM;
    const size_t qg = (size_t)(q0 + q_loc) * DM + hc;
    #pragma unroll
    for (int jj = 0; jj < 4; ++jj) {
        h16x4 ov = { (h16)o[jj][0], (h16)o[jj][1],
                     (h16)o[jj][2], (h16)o[jj][3] };
        *(h16x4*)(op + qg + jj * 16 + lq * 4) = ov;
    }
    if (lq == 0) {   // one lane per q-row (all lq agree after xor16/32)
        const size_t mi = ((size_t)sp * NH + hh) * SEQ + q0 + q_loc;
        Mb[mi] = m_st;
        Lb[mi] = l_st;
    }
}

// ---------------------------------------------------------------------------
// Combine NS partials: O = sum_s w_s*O_s / sum_s w_s*l_s, w_s = exp2(m_s-m*).
// One thread per 4 d-columns of one q-row.
// ---------------------------------------------------------------------------
__global__ __launch_bounds__(256) void combine(const h16* __restrict__ OP,
                                               const float* __restrict__ Mb,
                                               const float* __restrict__ Lb,
                                               h16* __restrict__ AOh) {
    const int i  = blockIdx.x * 256 + threadIdx.x;   // 1M threads
    const int q  = i >> 8;
    const int c4 = (i & 255) * 4;
    const int hh = c4 >> 6;

    float ms[NS], ls[NS];
    float mstar = -1e30f;
    #pragma unroll
    for (int s = 0; s < NS; ++s) {
        const size_t mi = ((size_t)s * NH + hh) * SEQ + q;
        ms[s] = Mb[mi];
        ls[s] = Lb[mi];
        mstar = fmaxf(mstar, ms[s]);
    }
    float L = 0.0f;
    float acc[4] = {};
    #pragma unroll
    for (int s = 0; s < NS; ++s) {
        const float ws = exp2f(ms[s] - mstar);
        L += ls[s] * ws;
        const h16x4 ov = *(const h16x4*)(OP + (size_t)s * SEQ * DM + (size_t)q * DM + c4);
        acc[0] += ws * (float)ov[0];
        acc[1] += ws * (float)ov[1];
        acc[2] += ws * (float)ov[2];
        acc[3] += ws * (float)ov[3];
    }
    const float inv = 1.0f / L;
    h16x4 r = { (h16)(acc[0] * inv), (h16)(acc[1] * inv),
                (h16)(acc[2] * inv), (h16)(acc[3] * inv) };
    *(h16x4*)(AOh + (size_t)q * DM + c4) = r;
}

// ---------------------------------------------------------------------------
extern "C" void kernel_launch(void* const* d_in, const int* in_sizes, int n_in,
                              void* d_out, int out_size, void* d_ws, size_t ws_size,
                              hipStream_t stream) {
    const float* x  = (const float*)d_in[0];
    const float* Wq = (const float*)d_in[1];
    const float* Wk = (const float*)d_in[2];
    const float* Wv = (const float*)d_in[3];
    const float* Wo = (const float*)d_in[4];
    float* out = (float*)d_out;

    const size_t SD = (size_t)SEQ * DM;   // 4M
    const size_t DD = (size_t)DM * DM;    // 1M

    h16* xh  = (h16*)d_ws;                // cvt_all relies on this contiguity
    h16* wqh = xh + SD;
    h16* wkh = wqh + DD;
    h16* wvh = wkh + DD;
    h16* woh = wvh + DD;
    h16* Qh  = woh + DD;
    h16* Kh  = Qh + SD;
    h16* Vth = Kh + SD;                   // transposed: [DM][SEQ]
    h16* AOh = Vth + SD;
    h16* OP  = AOh + SD;                  // NS partial O buffers
    float* Mb = (float*)(OP + (size_t)NS * SD);
    float* Lb = Mb + (size_t)NS * NH * SEQ;

    const dim3 blk(256);

    cvt_all<<<(int)((SD + 4 * DD) / 4 / 256), blk, 0, stream>>>(x, Wq, Wk, Wv, Wo, xh);

    // Q pre-scaled by 1/sqrt(DH) * log2(e) for the exp2-domain softmax
    const float SCL = 0.125f * 1.44269504088896340736f;

    gemm_qkv<<<dim3(DM / 128, SEQ / 128, 3), blk, 0, stream>>>(
        xh, wqh, wkh, wvh, Qh, Kh, Vth, SCL);

    flash_attn_split<<<dim3(NH, 64, NS), blk, 0, stream>>>(Qh, Kh, Vth, OP, Mb, Lb);

    combine<<<(int)(SD / 4 / 256), blk, 0, stream>>>(OP, Mb, Lb, AOh);

    gemm_out<<<dim3(DM / 128, SEQ / 64), blk, 0, stream>>>(AOh, woh, out);
}

// Round 5
// 219.874 us; speedup vs baseline: 1.1365x; 1.0102x over previous
//
#include <hip/hip_runtime.h>
#include <math.h>

#define SEQ 4096
#define DM  1024
#define NH  16
#define DH  64
#define NS  4      // k-splits per q-tile

typedef _Float16 h16;
typedef __attribute__((ext_vector_type(4))) _Float16 h16x4;
typedef __attribute__((ext_vector_type(8))) _Float16 h16x8;
typedef __attribute__((ext_vector_type(4))) float f32x4;

// async global->LDS, 16B per lane, dest = wave-uniform base + lane*16
__device__ __forceinline__ void gload_lds16(const h16* g, h16* l) {
    __builtin_amdgcn_global_load_lds(
        (const __attribute__((address_space(1))) void*)g,
        (__attribute__((address_space(3))) void*)l, 16, 0, 0);
}

// ---------------------------------------------------------------------------
// Single fused fp32 -> fp16 conversion for x + all 4 weights.
// ---------------------------------------------------------------------------
__global__ __launch_bounds__(256) void cvt_all(const float* __restrict__ x,
                                               const float* __restrict__ wq,
                                               const float* __restrict__ wk,
                                               const float* __restrict__ wv,
                                               const float* __restrict__ wo,
                                               h16* __restrict__ dst) {
    const size_t SD4 = (size_t)SEQ * DM / 4;   // 1M float4s
    const size_t DD4 = (size_t)DM * DM / 4;    // 256K float4s
    const size_t i = (size_t)blockIdx.x * 256 + threadIdx.x;
    const float* src;
    size_t off;
    if (i < SD4) { src = x; off = i; }
    else {
        const size_t j = i - SD4;
        const int wsel = (int)(j >> 18);       // DD4 = 2^18
        off = j & (DD4 - 1);
        src = (wsel == 0) ? wq : (wsel == 1) ? wk : (wsel == 2) ? wv : wo;
    }
    const float4 v = ((const float4*)src)[off];
    h16x4 o = { (h16)v.x, (h16)v.y, (h16)v.z, (h16)v.w };
    ((h16x4*)dst)[i] = o;
}

// ---------------------------------------------------------------------------
// m97-style MFMA GEMM: 128x128 tile, BK=64 (two 32-slabs), global_load_lds
// width-16 staging into unpadded GT=32 layout. 4 waves, 4x4 frags.
// Layouts: Q/K plain [SEQ][DM] (scaled Q), V^T [DM][SEQ].
// ---------------------------------------------------------------------------
#define GT 32

// z = 0,1,2 -> Q (scaled), K, V^T outputs
__global__ __launch_bounds__(256) void gemm_qkv(const h16* __restrict__ xh,
                                                const h16* __restrict__ Wq,
                                                const h16* __restrict__ Wk,
                                                const h16* __restrict__ Wv,
                                                h16* __restrict__ Qh,
                                                h16* __restrict__ Kh,
                                                h16* __restrict__ Vth,
                                                float scl) {
    __shared__ h16 As[2][128 * GT];
    __shared__ h16 Bs[2][128 * GT];

    const int z    = blockIdx.z;
    const h16* B   = (z == 0) ? Wq : (z == 1) ? Wk : Wv;
    const int t    = threadIdx.x;
    const int lane = t & 63;
    const int w    = t >> 6;
    const int wm   = (w >> 1) * 64;
    const int wn   = (w & 1) * 64;
    const int l15  = lane & 15;
    const int lq   = lane >> 4;
    const int lq8  = lq * 8;
    const int m0   = blockIdx.y * 128;
    const int n0   = blockIdx.x * 128;
    const int K = DM, M = SEQ, N = DM;

    const int srow = w * 16 + (lane >> 2);
    const int scol = (lane & 3) * 8;
    const h16* pa0 = xh + (size_t)(m0 + srow) * K + scol;
    const h16* pa1 = xh + (size_t)(m0 + 64 + srow) * K + scol;
    const h16* pb0 = B  + (size_t)(n0 + srow) * K + scol;
    const h16* pb1 = B  + (size_t)(n0 + 64 + srow) * K + scol;

    f32x4 acc[4][4] = {};

    for (int k0 = 0; k0 < K; k0 += 64) {
        __syncthreads();
        #pragma unroll
        for (int s = 0; s < 2; ++s) {
            const int ko = k0 + s * 32;
            gload_lds16(pa0 + ko, &As[s][w * 512]);
            gload_lds16(pa1 + ko, &As[s][2048 + w * 512]);
            gload_lds16(pb0 + ko, &Bs[s][w * 512]);
            gload_lds16(pb1 + ko, &Bs[s][2048 + w * 512]);
        }
        __syncthreads();

        #pragma unroll
        for (int s = 0; s < 2; ++s) {
            h16x8 af[4], bf[4];
            #pragma unroll
            for (int i = 0; i < 4; ++i)
                af[i] = *(const h16x8*)&As[s][(wm + i * 16 + l15) * GT + lq8];
            #pragma unroll
            for (int j = 0; j < 4; ++j)
                bf[j] = *(const h16x8*)&Bs[s][(wn + j * 16 + l15) * GT + lq8];
            #pragma unroll
            for (int i = 0; i < 4; ++i)
                #pragma unroll
                for (int j = 0; j < 4; ++j)
                    acc[i][j] = __builtin_amdgcn_mfma_f32_16x16x32_f16(af[i], bf[j], acc[i][j], 0, 0, 0);
        }
    }

    const int cr = wm + lq * 4;
    const int cc = wn + l15;
    if (z == 2) {   // V^T: h16 [N][M], vectorized along M
        #pragma unroll
        for (int i = 0; i < 4; ++i)
            #pragma unroll
            for (int j = 0; j < 4; ++j) {
                const int gm0 = m0 + cr + i * 16;
                const int gn  = n0 + cc + j * 16;
                h16x4 v = { (h16)acc[i][j][0], (h16)acc[i][j][1],
                            (h16)acc[i][j][2], (h16)acc[i][j][3] };
                *(h16x4*)(Vth + (size_t)gn * M + gm0) = v;
            }
    } else {
        h16* Og = (z == 0) ? Qh : Kh;
        const float e = (z == 0) ? scl : 1.0f;
        #pragma unroll
        for (int i = 0; i < 4; ++i)
            #pragma unroll
            for (int j = 0; j < 4; ++j)
                #pragma unroll
                for (int r = 0; r < 4; ++r) {
                    const int gm = m0 + cr + i * 16 + r;
                    const int gn = n0 + cc + j * 16;
                    Og[(size_t)gm * N + gn] = (h16)(acc[i][j][r] * e);
                }
    }
}

// out[M][N] (f32) = AO (h16) @ Wo^T (h16). 64x128 tile -> grid 512 = 2/CU.
__global__ __launch_bounds__(256) void gemm_out(const h16* __restrict__ A,
                                                const h16* __restrict__ B,
                                                float* __restrict__ C) {
    __shared__ h16 As[2][64 * GT];
    __shared__ h16 Bs[2][128 * GT];

    const int t    = threadIdx.x;
    const int lane = t & 63;
    const int w    = t >> 6;
    const int wm   = (w >> 1) * 32;
    const int wn   = (w & 1) * 64;
    const int l15  = lane & 15;
    const int lq   = lane >> 4;
    const int lq8  = lq * 8;
    const int m0   = blockIdx.y * 64;
    const int n0   = blockIdx.x * 128;
    const int K = DM, N = DM;

    const int srow = w * 16 + (lane >> 2);
    const int scol = (lane & 3) * 8;
    const h16* pa0 = A + (size_t)(m0 + srow) * K + scol;
    const h16* pb0 = B + (size_t)(n0 + srow) * K + scol;
    const h16* pb1 = B + (size_t)(n0 + 64 + srow) * K + scol;

    f32x4 acc[2][4] = {};

    for (int k0 = 0; k0 < K; k0 += 64) {
        __syncthreads();
        #pragma unroll
        for (int s = 0; s < 2; ++s) {
            const int ko = k0 + s * 32;
            gload_lds16(pa0 + ko, &As[s][w * 512]);
            gload_lds16(pb0 + ko, &Bs[s][w * 512]);
            gload_lds16(pb1 + ko, &Bs[s][2048 + w * 512]);
        }
        __syncthreads();

        #pragma unroll
        for (int s = 0; s < 2; ++s) {
            h16x8 af[2], bf[4];
            #pragma unroll
            for (int i = 0; i < 2; ++i)
                af[i] = *(const h16x8*)&As[s][(wm + i * 16 + l15) * GT + lq8];
            #pragma unroll
            for (int j = 0; j < 4; ++j)
                bf[j] = *(const h16x8*)&Bs[s][(wn + j * 16 + l15) * GT + lq8];
            #pragma unroll
            for (int i = 0; i < 2; ++i)
                #pragma unroll
                for (int j = 0; j < 4; ++j)
                    acc[i][j] = __builtin_amdgcn_mfma_f32_16x16x32_f16(af[i], bf[j], acc[i][j], 0, 0, 0);
        }
    }

    const int cr = wm + lq * 4;
    const int cc = wn + l15;
    #pragma unroll
    for (int i = 0; i < 2; ++i)
        #pragma unroll
        for (int j = 0; j < 4; ++j)
            #pragma unroll
            for (int r = 0; r < 4; ++r)
                C[(size_t)(m0 + cr + i * 16 + r) * N + n0 + cc + j * 16] = acc[i][j][r];
}

// ---------------------------------------------------------------------------
// SPLIT-K MFMA flash attention (causal), S^T formulation, exp2 domain.
// Register-P PV (S^T C-layout == 16x16x16 B-operand layout, no P LDS trip).
// THIS ROUND: each wave owns TWO 16-q bands (q and q+64) of a 128-q block.
// The kf/vf LDS fragments are identical for both halves (and for all waves),
// so every LDS read now feeds 2 MFMAs -> LDS bytes per unit work HALVED,
// and block-iterations/barriers/staging per work halved (was the ~60%-busy
// LDS pipe + 4x wave read amplification). Double-buffered, 1 barrier/tile.
// ---------------------------------------------------------------------------
#define AST 80
#define VST 72

__global__ __launch_bounds__(256, 3) void flash_attn_split(
        const h16* __restrict__ Qg, const h16* __restrict__ Kg,
        const h16* __restrict__ Vt, h16* __restrict__ OP,
        float* __restrict__ Mb, float* __restrict__ Lb) {
    __shared__ h16 Ks[2][64 * AST];   // [buf][k_local][d]
    __shared__ h16 Vs[2][64 * VST];   // [buf][d][k_local]

    const int jq   = 31 - (int)blockIdx.y;   // big chunks dispatch first
    const int hh   = blockIdx.x;
    const int sp   = blockIdx.z;
    const int t    = threadIdx.x;
    const int lane = t & 63;
    const int w    = t >> 6;
    const int l15  = lane & 15;
    const int lq   = lane >> 4;
    const int lq8  = lq * 8;
    const int hc   = hh * DH;
    const int q0   = jq * 128;
    const int qa   = w * 16 + l15;           // local q within each 64-half
    const int diag1 = 2 * jq;                // diagonal k-tile of half 1
    const int diag2 = 2 * jq + 1;            // diagonal k-tile of half 2

    const int ntile = 2 * jq + 2;
    const int chunk = (ntile + NS - 1) / NS;
    const int kts   = sp * chunk;
    const int kte   = (kts + chunk < ntile) ? (kts + chunk) : ntile;

    const int r1 = t >> 3;             // 0..31
    const int r2 = r1 + 32;
    const int c1 = (t & 7) * 8;

    // Q fragments for both halves: direct global reads (one-time per block)
    const size_t qrow1 = (size_t)(q0 + qa) * DM + hc;
    const size_t qrow2 = (size_t)(q0 + 64 + qa) * DM + hc;
    h16x8 qf[2][2];
    qf[0][0] = *(const h16x8*)(Qg + qrow1 + lq8);
    qf[0][1] = *(const h16x8*)(Qg + qrow1 + 32 + lq8);
    qf[1][0] = *(const h16x8*)(Qg + qrow2 + lq8);
    qf[1][1] = *(const h16x8*)(Qg + qrow2 + 32 + lq8);

    // preload first K/V tile of this split (kts*64 <= 3072: in-bounds)
    const int kb0 = kts * 64;
    h16x8 kv1 = *(const h16x8*)(Kg + (size_t)(kb0 + r1) * DM + hc + c1);
    h16x8 kv2 = *(const h16x8*)(Kg + (size_t)(kb0 + r2) * DM + hc + c1);
    h16x8 vv1 = *(const h16x8*)(Vt + (size_t)(hc + r1) * SEQ + kb0 + c1);
    h16x8 vv2 = *(const h16x8*)(Vt + (size_t)(hc + r2) * SEQ + kb0 + c1);

    float m_st[2] = { -1e30f, -1e30f };
    float l_st[2] = { 0.0f, 0.0f };      // PER-LANE partial sums
    f32x4 o[2][4] = {};
    int bb = 0;

    for (int kt = kts; kt < kte; ++kt) {
        // stage tile kt into buf bb (regs loaded last iteration)
        *(h16x8*)&Ks[bb][r1 * AST + c1] = kv1;
        *(h16x8*)&Ks[bb][r2 * AST + c1] = kv2;
        *(h16x8*)&Vs[bb][r1 * VST + c1] = vv1;
        *(h16x8*)&Vs[bb][r2 * VST + c1] = vv2;
        __syncthreads();
        if (kt + 1 < kte) {   // prefetch next K/V tile (covered by compute)
            const int k0n = (kt + 1) * 64;
            kv1 = *(const h16x8*)(Kg + (size_t)(k0n + r1) * DM + hc + c1);
            kv2 = *(const h16x8*)(Kg + (size_t)(k0n + r2) * DM + hc + c1);
            vv1 = *(const h16x8*)(Vt + (size_t)(hc + r1) * SEQ + k0n + c1);
            vv2 = *(const h16x8*)(Vt + (size_t)(hc + r2) * SEQ + k0n + c1);
        }

        // ---- S^T = K Q^T for both q-halves; kf shared ----
        f32x4 s[2][4] = {};
        #pragma unroll
        for (int kc = 0; kc < 2; ++kc) {
            h16x8 kf[4];
            #pragma unroll
            for (int jj = 0; jj < 4; ++jj)
                kf[jj] = *(const h16x8*)&Ks[bb][(jj * 16 + l15) * AST + kc * 32 + lq8];
            #pragma unroll
            for (int jj = 0; jj < 4; ++jj)
                s[0][jj] = __builtin_amdgcn_mfma_f32_16x16x32_f16(kf[jj], qf[0][kc], s[0][jj], 0, 0, 0);
            #pragma unroll
            for (int jj = 0; jj < 4; ++jj)
                s[1][jj] = __builtin_amdgcn_mfma_f32_16x16x32_f16(kf[jj], qf[1][kc], s[1][jj], 0, 0, 0);
        }

        // ---- causal masks (block-uniform outer branches) ----
        if (kt >= diag1) {   // half 1: partial at diag1, full beyond
            const int rel = (q0 + qa) - kt * 64;
            #pragma unroll
            for (int jj = 0; jj < 4; ++jj)
                #pragma unroll
                for (int r = 0; r < 4; ++r)
                    if ((jj * 16 + lq * 4 + r) > rel) s[0][jj][r] = -1e30f;
        }
        if (kt >= diag2) {   // half 2: partial at diag2 (last tile)
            const int rel = (q0 + 64 + qa) - kt * 64;
            #pragma unroll
            for (int jj = 0; jj < 4; ++jj)
                #pragma unroll
                for (int r = 0; r < 4; ++r)
                    if ((jj * 16 + lq * 4 + r) > rel) s[1][jj][r] = -1e30f;
        }

        // ---- online softmax (in-register), both halves ----
        h16x4 pk[2][4];
        #pragma unroll
        for (int h = 0; h < 2; ++h) {
            float mx = -1e30f;
            #pragma unroll
            for (int jj = 0; jj < 4; ++jj)
                #pragma unroll
                for (int r = 0; r < 4; ++r)
                    mx = fmaxf(mx, s[h][jj][r]);
            mx = fmaxf(mx, __shfl_xor(mx, 16, 64));
            mx = fmaxf(mx, __shfl_xor(mx, 32, 64));
            // defer-max: rescale only when tile max grows by >5 (exp2 domain:
            // P bounded by 2^5, fp16-safe). mx uniform over a q-row's 4 lanes.
            if (mx > m_st[h] + 5.0f) {
                const float alpha = exp2f(m_st[h] - mx);
                m_st[h] = mx;
                l_st[h] *= alpha;
                #pragma unroll
                for (int jj = 0; jj < 4; ++jj)
                    #pragma unroll
                    for (int r = 0; r < 4; ++r)
                        o[h][jj][r] *= alpha;
            }
            #pragma unroll
            for (int jj = 0; jj < 4; ++jj) {
                const float p0 = exp2f(s[h][jj][0] - m_st[h]);
                const float p1 = exp2f(s[h][jj][1] - m_st[h]);
                const float p2 = exp2f(s[h][jj][2] - m_st[h]);
                const float p3 = exp2f(s[h][jj][3] - m_st[h]);
                l_st[h] += (p0 + p1) + (p2 + p3);
                pk[h][jj] = h16x4{ (h16)p0, (h16)p1, (h16)p2, (h16)p3 };
            }
        }

        // ---- O^T += V^T P^T (16x16x16 MFMA); vf shared by both halves ----
        #pragma unroll
        for (int dd = 0; dd < 4; ++dd)
            #pragma unroll
            for (int jj = 0; jj < 4; ++jj) {
                const h16x4 vf = *(const h16x4*)&Vs[bb][(dd * 16 + l15) * VST + jj * 16 + lq * 4];
                o[0][dd] = __builtin_amdgcn_mfma_f32_16x16x16f16(vf, pk[0][jj], o[0][dd], 0, 0, 0);
                o[1][dd] = __builtin_amdgcn_mfma_f32_16x16x16f16(vf, pk[1][jj], o[1][dd], 0, 0, 0);
            }

        bb ^= 1;
    }

    // fold the per-lane partial sums (q-row spread over 4 lanes via lq)
    #pragma unroll
    for (int h = 0; h < 2; ++h) {
        l_st[h] += __shfl_xor(l_st[h], 16, 64);
        l_st[h] += __shfl_xor(l_st[h], 32, 64);
    }

    // ---- epilogue: write UNNORMALIZED partial O + (m, l), both halves ----
    h16* const op = OP + (size_t)sp * SEQ * DM;
    #pragma unroll
    for (int h = 0; h < 2; ++h) {
        const int qg_row = q0 + h * 64 + qa;
        const size_t qg = (size_t)qg_row * DM + hc;
        #pragma unroll
        for (int jj = 0; jj < 4; ++jj) {
            h16x4 ov = { (h16)o[h][jj][0], (h16)o[h][jj][1],
                         (h16)o[h][jj][2], (h16)o[h][jj][3] };
            *(h16x4*)(op + qg + jj * 16 + lq * 4) = ov;
        }
        if (lq == 0) {   // one lane per q-row (all lq agree after xor16/32)
            const size_t mi = ((size_t)sp * NH + hh) * SEQ + qg_row;
            Mb[mi] = m_st[h];
            Lb[mi] = l_st[h];
        }
    }
}

// ---------------------------------------------------------------------------
// Combine NS partials: O = sum_s w_s*O_s / sum_s w_s*l_s, w_s = exp2(m_s-m*).
// One thread per 4 d-columns of one q-row.
// ---------------------------------------------------------------------------
__global__ __launch_bounds__(256) void combine(const h16* __restrict__ OP,
                                               const float* __restrict__ Mb,
                                               const float* __restrict__ Lb,
                                               h16* __restrict__ AOh) {
    const int i  = blockIdx.x * 256 + threadIdx.x;   // 1M threads
    const int q  = i >> 8;
    const int c4 = (i & 255) * 4;
    const int hh = c4 >> 6;

    float ms[NS], ls[NS];
    float mstar = -1e30f;
    #pragma unroll
    for (int s = 0; s < NS; ++s) {
        const size_t mi = ((size_t)s * NH + hh) * SEQ + q;
        ms[s] = Mb[mi];
        ls[s] = Lb[mi];
        mstar = fmaxf(mstar, ms[s]);
    }
    float L = 0.0f;
    float acc[4] = {};
    #pragma unroll
    for (int s = 0; s < NS; ++s) {
        const float ws = exp2f(ms[s] - mstar);
        L += ls[s] * ws;
        const h16x4 ov = *(const h16x4*)(OP + (size_t)s * SEQ * DM + (size_t)q * DM + c4);
        acc[0] += ws * (float)ov[0];
        acc[1] += ws * (float)ov[1];
        acc[2] += ws * (float)ov[2];
        acc[3] += ws * (float)ov[3];
    }
    const float inv = 1.0f / L;
    h16x4 r = { (h16)(acc[0] * inv), (h16)(acc[1] * inv),
                (h16)(acc[2] * inv), (h16)(acc[3] * inv) };
    *(h16x4*)(AOh + (size_t)q * DM + c4) = r;
}

// ---------------------------------------------------------------------------
extern "C" void kernel_launch(void* const* d_in, const int* in_sizes, int n_in,
                              void* d_out, int out_size, void* d_ws, size_t ws_size,
                              hipStream_t stream) {
    const float* x  = (const float*)d_in[0];
    const float* Wq = (const float*)d_in[1];
    const float* Wk = (const float*)d_in[2];
    const float* Wv = (const float*)d_in[3];
    const float* Wo = (const float*)d_in[4];
    float* out = (float*)d_out;

    const size_t SD = (size_t)SEQ * DM;   // 4M
    const size_t DD = (size_t)DM * DM;    // 1M

    h16* xh  = (h16*)d_ws;                // cvt_all relies on this contiguity
    h16* wqh = xh + SD;
    h16* wkh = wqh + DD;
    h16* wvh = wkh + DD;
    h16* woh = wvh + DD;
    h16* Qh  = woh + DD;
    h16* Kh  = Qh + SD;
    h16* Vth = Kh + SD;                   // transposed: [DM][SEQ]
    h16* AOh = Vth + SD;
    h16* OP  = AOh + SD;                  // NS partial O buffers
    float* Mb = (float*)(OP + (size_t)NS * SD);
    float* Lb = Mb + (size_t)NS * NH * SEQ;

    const dim3 blk(256);

    cvt_all<<<(int)((SD + 4 * DD) / 4 / 256), blk, 0, stream>>>(x, Wq, Wk, Wv, Wo, xh);

    // Q pre-scaled by 1/sqrt(DH) * log2(e) for the exp2-domain softmax
    const float SCL = 0.125f * 1.44269504088896340736f;

    gemm_qkv<<<dim3(DM / 128, SEQ / 128, 3), blk, 0, stream>>>(
        xh, wqh, wkh, wvh, Qh, Kh, Vth, SCL);

    flash_attn_split<<<dim3(NH, 32, NS), blk, 0, stream>>>(Qh, Kh, Vth, OP, Mb, Lb);

    combine<<<(int)(SD / 4 / 256), blk, 0, stream>>>(OP, Mb, Lb, AOh);

    gemm_out<<<dim3(DM / 128, SEQ / 64), blk, 0, stream>>>(AOh, woh, out);
}